// Round 8
// baseline (494.598 us; speedup 1.0000x reference)
//
#include <hip/hip_runtime.h>

#define H 1024
#define W 1024
#define NIMG 8
#define CPT 4                  // columns per thread
#define TH 16                  // output rows per wave-tile
#define NBX 4                  // 64 lanes * 4 cols * 4 = 1024 cols
#define NBYT (H / TH)          // 64 y-tiles
#define NWAVES (NBX * NBYT * NIMG)   // 2048
#define EPS 1e-5f

struct RS { float I[CPT], J[CPT], II[CPT], JJ[CPT], IJ[CPT]; };

// Load 12 raw px of I and J for one row (aligned float4, edge-guarded).
__device__ __forceinline__ void load_row12(const float* __restrict__ Ip,
                                           const float* __restrict__ Jp,
                                           int r, int X, bool okL, bool okR,
                                           float* __restrict__ a,
                                           float* __restrict__ b) {
  if ((unsigned)r < (unsigned)H) {
    const float* Ir = Ip + (size_t)r * W;
    const float* Jr = Jp + (size_t)r * W;
    { float4 q = *reinterpret_cast<const float4*>(Ir + X);
      a[4]=q.x; a[5]=q.y; a[6]=q.z; a[7]=q.w;
      float4 p = *reinterpret_cast<const float4*>(Jr + X);
      b[4]=p.x; b[5]=p.y; b[6]=p.z; b[7]=p.w; }
    if (okL) {
      float4 q = *reinterpret_cast<const float4*>(Ir + X - 4);
      a[0]=q.x; a[1]=q.y; a[2]=q.z; a[3]=q.w;
      float4 p = *reinterpret_cast<const float4*>(Jr + X - 4);
      b[0]=p.x; b[1]=p.y; b[2]=p.z; b[3]=p.w;
    } else { a[0]=a[1]=a[2]=a[3]=0.f; b[0]=b[1]=b[2]=b[3]=0.f; }
    if (okR) {
      float4 q = *reinterpret_cast<const float4*>(Ir + X + 4);
      a[8]=q.x; a[9]=q.y; a[10]=q.z; a[11]=q.w;
      float4 p = *reinterpret_cast<const float4*>(Jr + X + 4);
      b[8]=p.x; b[9]=p.y; b[10]=p.z; b[11]=p.w;
    } else { a[8]=a[9]=a[10]=a[11]=0.f; b[8]=b[9]=b[10]=b[11]=0.f; }
  } else {
    #pragma unroll
    for (int k = 0; k < 12; ++k) { a[k] = 0.f; b[k] = 0.f; }
  }
}

// Horizontal 9-box rowsums for 4 consecutive output columns.
__device__ __forceinline__ void rs4(const float* __restrict__ a,
                                    const float* __restrict__ b, RS& o) {
  float sI=0.f, sJ=0.f, sII=0.f, sJJ=0.f, sIJ=0.f;
  #pragma unroll
  for (int k = 0; k < 9; ++k) {
    sI += a[k]; sJ += b[k];
    sII = fmaf(a[k], a[k], sII);
    sJJ = fmaf(b[k], b[k], sJJ);
    sIJ = fmaf(a[k], b[k], sIJ);
  }
  o.I[0]=sI; o.J[0]=sJ; o.II[0]=sII; o.JJ[0]=sJJ; o.IJ[0]=sIJ;
  #pragma unroll
  for (int i = 1; i < CPT; ++i) {
    float an=a[i+8], al=a[i-1], bn=b[i+8], bl=b[i-1];
    sI += an - al;  sJ += bn - bl;
    sII = fmaf(-al, al, fmaf(an, an, sII));
    sJJ = fmaf(-bl, bl, fmaf(bn, bn, sJJ));
    sIJ = fmaf(-al, bl, fmaf(an, bn, sIJ));
    o.I[i]=sI; o.J[i]=sJ; o.II[i]=sII; o.JJ[i]=sJJ; o.IJ[i]=sIJ;
  }
}

// 1-wave blocks, no LDS, no barriers; fully unrolled walking-column tile.
__global__ __launch_bounds__(64, 2)
void ncc_main(const float* __restrict__ I, const float* __restrict__ J,
              float* __restrict__ partial) {
  const int lane = threadIdx.x;           // 0..63
  const int X  = blockIdx.x * 256 + lane * CPT;
  const int y0 = blockIdx.y * TH;
  const bool okL = (X >= 4);
  const bool okR = (X + 8 <= W);
  const size_t img_off = (size_t)blockIdx.z * H * W;
  const float* Ip = I + img_off;
  const float* Jp = J + img_off;

  float wI[CPT], wJ[CPT], wII[CPT], wJJ[CPT], wIJ[CPT];
  #pragma unroll
  for (int i = 0; i < CPT; ++i) { wI[i]=wJ[i]=wII[i]=wJJ[i]=wIJ[i]=0.f; }
  float acc = 0.f;
  const float inv81 = 1.0f / 81.0f;

  // ---- warm-up: rows y0-4 .. y0+3 (fully unrolled, loads batch by pairs) --
  #pragma unroll
  for (int k = 0; k < 8; ++k) {
    float a[12], b[12];
    load_row12(Ip, Jp, y0 - 4 + k, X, okL, okR, a, b);
    RS o; rs4(a, b, o);
    #pragma unroll
    for (int i = 0; i < CPT; ++i) {
      wI[i] += o.I[i];  wJ[i] += o.J[i];
      wII[i] += o.II[i]; wJJ[i] += o.JJ[i]; wIJ[i] += o.IJ[i];
    }
  }
  // ---- first output row: add y0+4, emit y0 ----
  {
    float a[12], b[12];
    load_row12(Ip, Jp, y0 + 4, X, okL, okR, a, b);
    RS o; rs4(a, b, o);
    #pragma unroll
    for (int i = 0; i < CPT; ++i) {
      wI[i] += o.I[i];  wJ[i] += o.J[i];
      wII[i] += o.II[i]; wJJ[i] += o.JJ[i]; wIJ[i] += o.IJ[i];
      float cross = fmaf(-(wI[i] * wJ[i]), inv81, wIJ[i]);
      float Iv    = fmaf(-(wI[i] * wI[i]), inv81, wII[i]);
      float Jv    = fmaf(-(wJ[i] * wJ[i]), inv81, wJJ[i]);
      acc = fmaf(cross * cross,
                 __builtin_amdgcn_rcpf(fmaf(Iv, Jv, EPS)), acc);
    }
  }
  // ---- steady state: enter y0+5+k, leave y0-4+k, emit y0+1+k ----
  #pragma unroll
  for (int k = 0; k < TH - 1; ++k) {
    float ae[12], be[12], al_[12], bl_[12];
    // all 12 float4 loads issued before any arithmetic
    load_row12(Ip, Jp, y0 + 5 + k, X, okL, okR, ae, be);
    load_row12(Ip, Jp, y0 - 4 + k, X, okL, okR, al_, bl_);
    RS oe, ol;
    rs4(ae, be, oe);
    rs4(al_, bl_, ol);
    #pragma unroll
    for (int i = 0; i < CPT; ++i) {
      wI[i]  += oe.I[i]  - ol.I[i];
      wJ[i]  += oe.J[i]  - ol.J[i];
      wII[i] += oe.II[i] - ol.II[i];
      wJJ[i] += oe.JJ[i] - ol.JJ[i];
      wIJ[i] += oe.IJ[i] - ol.IJ[i];
      float cross = fmaf(-(wI[i] * wJ[i]), inv81, wIJ[i]);
      float Iv    = fmaf(-(wI[i] * wI[i]), inv81, wII[i]);
      float Jv    = fmaf(-(wJ[i] * wJ[i]), inv81, wJJ[i]);
      acc = fmaf(cross * cross,
                 __builtin_amdgcn_rcpf(fmaf(Iv, Jv, EPS)), acc);
    }
  }

  // ---- wave reduction -> one partial per wave ----
  #pragma unroll
  for (int off = 32; off > 0; off >>= 1)
    acc += __shfl_down(acc, off, 64);
  if (lane == 0) {
    const int wid = ((int)blockIdx.z * NBYT + (int)blockIdx.y) * NBX
                    + (int)blockIdx.x;
    partial[wid] = acc;
  }
}

__global__ __launch_bounds__(256)
void ncc_reduce(const float* __restrict__ partial, float* __restrict__ out) {
  __shared__ float red[4];
  const int tid = threadIdx.x;
  const float4* p4 = reinterpret_cast<const float4*>(partial);
  float s = 0.f;
  #pragma unroll
  for (int i = tid; i < NWAVES / 4; i += 256) {
    float4 v = p4[i];
    s += (v.x + v.y) + (v.z + v.w);
  }
  #pragma unroll
  for (int off = 32; off > 0; off >>= 1)
    s += __shfl_down(s, off, 64);
  if ((tid & 63) == 0) red[tid >> 6] = s;
  __syncthreads();
  if (tid == 0)
    out[0] = (red[0] + red[1] + red[2] + red[3]) *
             (1.0f / (float)((size_t)NIMG * H * W));
}

extern "C" void kernel_launch(void* const* d_in, const int* in_sizes, int n_in,
                              void* d_out, int out_size, void* d_ws, size_t ws_size,
                              hipStream_t stream) {
  const float* I = (const float*)d_in[0];
  const float* J = (const float*)d_in[1];
  float* out     = (float*)d_out;
  float* partial = (float*)d_ws;            // 2048 * 4 B

  dim3 grid(NBX, NBYT, NIMG);               // 4 x 64 x 8 = 2048 one-wave blocks
  hipLaunchKernelGGL(ncc_main, grid, dim3(64), 0, stream, I, J, partial);
  hipLaunchKernelGGL(ncc_reduce, dim3(1), dim3(256), 0, stream, partial, out);
}

// Round 9
// 115.994 us; speedup vs baseline: 4.2640x; 4.2640x over previous
//
#include <hip/hip_runtime.h>

#define H 1024
#define W 1024
#define NIMG 8
#define CPT 4                  // columns per thread
#define TH 8                   // output rows per wave-tile
#define NBX 4                  // 64 lanes * 4 cols * 4 = 1024 cols
#define NBYT (H / TH)          // 128
#define NWAVES (NBX * NBYT * NIMG)   // 4096 single-wave blocks = 16/CU
#define EPS 1e-5f

struct RS { float I[CPT], J[CPT], II[CPT], JJ[CPT], IJ[CPT]; };

// Branchless 12-px row load (caller guarantees row r is valid).
// All 6 float4 loads are unconditional -> schedulable as one batch.
__device__ __forceinline__ void load12(const float* __restrict__ Ir,
                                       const float* __restrict__ Jr,
                                       int X, bool okL, bool okR,
                                       float4& iL, float4& iC, float4& iR,
                                       float4& jL, float4& jC, float4& jR) {
  const int xl = okL ? X - 4 : X;       // safe address when at left edge
  const int xr = okR ? X + 4 : X;       // safe address when at right edge
  iC = *reinterpret_cast<const float4*>(Ir + X);
  jC = *reinterpret_cast<const float4*>(Jr + X);
  iL = *reinterpret_cast<const float4*>(Ir + xl);
  jL = *reinterpret_cast<const float4*>(Jr + xl);
  iR = *reinterpret_cast<const float4*>(Ir + xr);
  jR = *reinterpret_cast<const float4*>(Jr + xr);
  if (!okL) { iL = make_float4(0.f,0.f,0.f,0.f); jL = make_float4(0.f,0.f,0.f,0.f); }
  if (!okR) { iR = make_float4(0.f,0.f,0.f,0.f); jR = make_float4(0.f,0.f,0.f,0.f); }
}

// Horizontal 9-box rowsums for 4 output columns from 12 raw px.
__device__ __forceinline__ void rowsum(const float4& iL, const float4& iC,
                                       const float4& iR, const float4& jL,
                                       const float4& jC, const float4& jR,
                                       RS& o) {
  const float a[12] = {iL.x,iL.y,iL.z,iL.w, iC.x,iC.y,iC.z,iC.w,
                       iR.x,iR.y,iR.z,iR.w};
  const float b[12] = {jL.x,jL.y,jL.z,jL.w, jC.x,jC.y,jC.z,jC.w,
                       jR.x,jR.y,jR.z,jR.w};
  float sI=0.f, sJ=0.f, sII=0.f, sJJ=0.f, sIJ=0.f;
  #pragma unroll
  for (int k = 0; k < 9; ++k) {
    sI += a[k]; sJ += b[k];
    sII = fmaf(a[k], a[k], sII);
    sJJ = fmaf(b[k], b[k], sJJ);
    sIJ = fmaf(a[k], b[k], sIJ);
  }
  o.I[0]=sI; o.J[0]=sJ; o.II[0]=sII; o.JJ[0]=sJJ; o.IJ[0]=sIJ;
  #pragma unroll
  for (int i = 1; i < CPT; ++i) {
    float an=a[i+8], al=a[i-1], bn=b[i+8], bl=b[i-1];
    sI += an - al;  sJ += bn - bl;
    sII = fmaf(-al, al, fmaf(an, an, sII));
    sJJ = fmaf(-bl, bl, fmaf(bn, bn, sJJ));
    sIJ = fmaf(-al, bl, fmaf(an, bn, sIJ));
    o.I[i]=sI; o.J[i]=sJ; o.II[i]=sII; o.JJ[i]=sJJ; o.IJ[i]=sIJ;
  }
}

// 1-wave blocks, no LDS, no barriers. Rolled loops (never unroll the tile
// walk: R8 showed full unroll -> 620 MB of scratch spill), big straight-line
// body with 12 batched loads for ILP.
__global__ __launch_bounds__(64, 4)
void ncc_main(const float* __restrict__ I, const float* __restrict__ J,
              float* __restrict__ partial) {
  const int lane = threadIdx.x;           // 0..63
  const int X  = blockIdx.x * 256 + lane * CPT;
  const int y0 = blockIdx.y * TH;
  const bool okL = (X >= 4);
  const bool okR = (X + 8 <= W);
  const size_t img_off = (size_t)blockIdx.z * H * W;
  const float* Ip = I + img_off;
  const float* Jp = J + img_off;

  float wI[CPT], wJ[CPT], wII[CPT], wJJ[CPT], wIJ[CPT];
  #pragma unroll
  for (int i = 0; i < CPT; ++i) { wI[i]=wJ[i]=wII[i]=wJJ[i]=wIJ[i]=0.f; }
  float acc = 0.f;
  const float inv81 = 1.0f / 81.0f;

  // ---- warm-up: rows y0-4 .. y0+4 (9 rows), window lands on output y0 ----
  #pragma unroll 1
  for (int k = 0; k < 9; ++k) {
    const int r = y0 - 4 + k;
    if ((unsigned)r < (unsigned)H) {      // wave-uniform branch
      float4 iL,iC,iR,jL,jC,jR;
      load12(Ip + (size_t)r * W, Jp + (size_t)r * W, X, okL, okR,
             iL,iC,iR,jL,jC,jR);
      RS o; rowsum(iL,iC,iR,jL,jC,jR,o);
      #pragma unroll
      for (int i = 0; i < CPT; ++i) {
        wI[i] += o.I[i];  wJ[i] += o.J[i];
        wII[i] += o.II[i]; wJJ[i] += o.JJ[i]; wIJ[i] += o.IJ[i];
      }
    }
  }
  // emit output row y0
  #pragma unroll
  for (int i = 0; i < CPT; ++i) {
    float cross = fmaf(-(wI[i] * wJ[i]), inv81, wIJ[i]);
    float Iv    = fmaf(-(wI[i] * wI[i]), inv81, wII[i]);
    float Jv    = fmaf(-(wJ[i] * wJ[i]), inv81, wJJ[i]);
    acc = fmaf(cross * cross,
               __builtin_amdgcn_rcpf(fmaf(Iv, Jv, EPS)), acc);
  }

  // ---- steady: enter y0+5+k, leave y0-4+k, emit y0+1+k ----
  #pragma unroll 1
  for (int k = 0; k < TH - 1; ++k) {
    const int re = y0 + 5 + k;
    const int rl = y0 - 4 + k;
    const bool ev = (unsigned)re < (unsigned)H;   // wave-uniform
    const bool lv = (unsigned)rl < (unsigned)H;   // wave-uniform
    if (ev & lv) {
      // fast path: all 12 float4 loads issued before any arithmetic
      float4 eiL,eiC,eiR,ejL,ejC,ejR, liL,liC,liR,ljL,ljC,ljR;
      load12(Ip + (size_t)re * W, Jp + (size_t)re * W, X, okL, okR,
             eiL,eiC,eiR,ejL,ejC,ejR);
      load12(Ip + (size_t)rl * W, Jp + (size_t)rl * W, X, okL, okR,
             liL,liC,liR,ljL,ljC,ljR);
      RS oe, ol;
      rowsum(eiL,eiC,eiR,ejL,ejC,ejR,oe);
      rowsum(liL,liC,liR,ljL,ljC,ljR,ol);
      #pragma unroll
      for (int i = 0; i < CPT; ++i) {
        wI[i]  += oe.I[i]  - ol.I[i];
        wJ[i]  += oe.J[i]  - ol.J[i];
        wII[i] += oe.II[i] - ol.II[i];
        wJJ[i] += oe.JJ[i] - ol.JJ[i];
        wIJ[i] += oe.IJ[i] - ol.IJ[i];
      }
    } else {
      if (ev) {
        float4 iL,iC,iR,jL,jC,jR;
        load12(Ip + (size_t)re * W, Jp + (size_t)re * W, X, okL, okR,
               iL,iC,iR,jL,jC,jR);
        RS o; rowsum(iL,iC,iR,jL,jC,jR,o);
        #pragma unroll
        for (int i = 0; i < CPT; ++i) {
          wI[i] += o.I[i];  wJ[i] += o.J[i];
          wII[i] += o.II[i]; wJJ[i] += o.JJ[i]; wIJ[i] += o.IJ[i];
        }
      }
      if (lv) {
        float4 iL,iC,iR,jL,jC,jR;
        load12(Ip + (size_t)rl * W, Jp + (size_t)rl * W, X, okL, okR,
               iL,iC,iR,jL,jC,jR);
        RS o; rowsum(iL,iC,iR,jL,jC,jR,o);
        #pragma unroll
        for (int i = 0; i < CPT; ++i) {
          wI[i] -= o.I[i];  wJ[i] -= o.J[i];
          wII[i] -= o.II[i]; wJJ[i] -= o.JJ[i]; wIJ[i] -= o.IJ[i];
        }
      }
    }
    #pragma unroll
    for (int i = 0; i < CPT; ++i) {
      float cross = fmaf(-(wI[i] * wJ[i]), inv81, wIJ[i]);
      float Iv    = fmaf(-(wI[i] * wI[i]), inv81, wII[i]);
      float Jv    = fmaf(-(wJ[i] * wJ[i]), inv81, wJJ[i]);
      acc = fmaf(cross * cross,
                 __builtin_amdgcn_rcpf(fmaf(Iv, Jv, EPS)), acc);
    }
  }

  // ---- wave reduction -> one partial per wave ----
  #pragma unroll
  for (int off = 32; off > 0; off >>= 1)
    acc += __shfl_down(acc, off, 64);
  if (lane == 0) {
    const int wid = ((int)blockIdx.z * NBYT + (int)blockIdx.y) * NBX
                    + (int)blockIdx.x;
    partial[wid] = acc;
  }
}

__global__ __launch_bounds__(256)
void ncc_reduce(const float* __restrict__ partial, float* __restrict__ out) {
  __shared__ float red[4];
  const int tid = threadIdx.x;
  const float4* p4 = reinterpret_cast<const float4*>(partial);
  float s = 0.f;
  #pragma unroll
  for (int i = tid; i < NWAVES / 4; i += 256) {
    float4 v = p4[i];
    s += (v.x + v.y) + (v.z + v.w);
  }
  #pragma unroll
  for (int off = 32; off > 0; off >>= 1)
    s += __shfl_down(s, off, 64);
  if ((tid & 63) == 0) red[tid >> 6] = s;
  __syncthreads();
  if (tid == 0)
    out[0] = (red[0] + red[1] + red[2] + red[3]) *
             (1.0f / (float)((size_t)NIMG * H * W));
}

extern "C" void kernel_launch(void* const* d_in, const int* in_sizes, int n_in,
                              void* d_out, int out_size, void* d_ws, size_t ws_size,
                              hipStream_t stream) {
  const float* I = (const float*)d_in[0];
  const float* J = (const float*)d_in[1];
  float* out     = (float*)d_out;
  float* partial = (float*)d_ws;            // 4096 * 4 B = 16 KiB

  dim3 grid(NBX, NBYT, NIMG);               // 4 x 128 x 8 = 4096 one-wave blocks
  hipLaunchKernelGGL(ncc_main, grid, dim3(64), 0, stream, I, J, partial);
  hipLaunchKernelGGL(ncc_reduce, dim3(1), dim3(256), 0, stream, partial, out);
}